// Round 7
// baseline (226.227 us; speedup 1.0000x reference)
//
#include <hip/hip_runtime.h>
#include <hip/hip_bf16.h>
#include <math.h>

#define LTOT   4096
#define EDIM   64
#define NMODES 64
#define BH     256
#define TWO_PI 6.28318530717958647692f

typedef float f32x4 __attribute__((ext_vector_type(4)));
typedef short s16x8 __attribute__((ext_vector_type(8)));

__device__ inline unsigned short f2bf(float f) {
    unsigned u = __builtin_bit_cast(unsigned, f);
    u += 0x7fff + ((u >> 16) & 1);           // round-to-nearest-even
    return (unsigned short)(u >> 16);
}
// compiler-friendly pack: emits v_cvt_pk_bf16_f32
__device__ inline unsigned packbf(float lo, float hi) {
    float2 t; t.x = lo; t.y = hi;
    __hip_bfloat162 h = __float22bfloat162_rn(t);
    unsigned r;
    __builtin_memcpy(&r, &h, 4);
    return r;
}
__device__ inline float bf2f(unsigned lo16) {
    return __builtin_bit_cast(float, lo16 << 16);
}

// ---------- All tables in one kernel (fewer launch gaps) ----------
// blocks 0..63: Tm[m=128][l] (cos / -sin rows); 64..1087: Tt[l][m]; 1088..2111: wtab
__global__ __launch_bounds__(256) void k_tables(const int* __restrict__ index,
                                                const float* __restrict__ w,
                                                unsigned short* __restrict__ Tm,
                                                unsigned short* __restrict__ Tt,
                                                unsigned* __restrict__ wt) {
    int b = blockIdx.x, t = threadIdx.x;
    if (b < 64) {
        int k = b, f = index[k];
        for (int l = t; l < LTOT; l += 256) {
            int m = (f * l) & (LTOT - 1);
            float th = (float)m * (TWO_PI / (float)LTOT);
            float s, c; sincosf(th, &s, &c);
            Tm[(size_t)(2 * k) * LTOT + l]     = f2bf(c);
            Tm[(size_t)(2 * k + 1) * LTOT + l] = f2bf(-s);
        }
    } else if (b < 64 + 1024) {
        int l = (b - 64) * 4 + (t >> 6);
        int k = t & 63, f = index[k];
        int m = (f * l) & (LTOT - 1);
        float th = (float)m * (TWO_PI / (float)LTOT);
        float s, c; sincosf(th, &s, &c);
        ((unsigned*)Tt)[l * 64 + k] = packbf(c, s);
    } else {
        int i = (b - 1088) * 256 + t;
        float2 v = ((const float2*)w)[i];
        wt[i] = packbf(v.x, v.y);
    }
}

// ---------- Stage 1: X[e][m] = sum_l xT[e][l] * T[l][m]  (MFMA bf16) ----------
// grid = BH*4 (bh, quarter-of-L partial), 256 threads (4 waves: 2 e-halves x 2 m-halves).
// SINGLE LDS buffer (17.4 KB -> 5 blocks/CU) + reg-prefetch of next tile under compute.
__global__ __launch_bounds__(256, 5) void k_stage1(const float* __restrict__ x,
                                                   const unsigned short* __restrict__ Tm,
                                                   float* __restrict__ Xp) {
    int bh = blockIdx.x >> 2, part = blockIdx.x & 3;
    const float* xb = x + ((size_t)bh * LTOT + part * 1024) * EDIM;
    __shared__ unsigned xT[64 * 68];              // [e=64][64+4 u32], XOR-swizzled

    int t = threadIdx.x;
    int q = t & 15, lp0 = t >> 4;                 // loader role
    int lane = t & 63, w = t >> 6;                // mfma role
    int r = lane & 15, kb8 = lane >> 4;
    int es = w & 1, ms = w >> 1;                  // e-half, m-half
    unsigned swzW = ((unsigned)(q & 7)) << 2;

    f32x4 acc[2][4];
    #pragma unroll
    for (int i = 0; i < 2; ++i)
        #pragma unroll
        for (int n = 0; n < 4; ++n) acc[i][n] = (f32x4)0.f;

    float4 xn[8];
    {   // prologue: load tile 0
        #pragma unroll
        for (int p = 0; p < 4; ++p) {
            const float* bp = xb + (size_t)(2 * (lp0 + p * 16)) * EDIM + 4 * q;
            xn[2 * p]     = *(const float4*)bp;
            xn[2 * p + 1] = *(const float4*)(bp + EDIM);
        }
    }
    for (int t8 = 0; t8 < 8; ++t8) {
        // stage regs -> LDS (bf16 pack, swizzled: exact 2-way banks = free)
        #pragma unroll
        for (int p = 0; p < 4; ++p) {
            float A0[4] = {xn[2*p].x, xn[2*p].y, xn[2*p].z, xn[2*p].w};
            float A1[4] = {xn[2*p+1].x, xn[2*p+1].y, xn[2*p+1].z, xn[2*p+1].w};
            #pragma unroll
            for (int j = 0; j < 4; ++j)
                xT[(4 * q + j) * 68 + (((unsigned)(lp0 + p * 16)) ^ swzW)] = packbf(A0[j], A1[j]);
        }
        __syncthreads();
        if (t8 < 7) {   // T14: issue next tile's loads now; land during compute
            const float* tb = xb + (size_t)((t8 + 1) * 128) * EDIM;
            #pragma unroll
            for (int p = 0; p < 4; ++p) {
                const float* bp = tb + (size_t)(2 * (lp0 + p * 16)) * EDIM + 4 * q;
                xn[2 * p]     = *(const float4*)bp;
                xn[2 * p + 1] = *(const float4*)(bp + EDIM);
            }
        }
        // compute tile t8
        #pragma unroll
        for (int kk = 0; kk < 4; ++kk) {
            s16x8 af[2];
            #pragma unroll
            for (int sub = 0; sub < 2; ++sub) {
                int row = es * 32 + sub * 16 + r;
                unsigned swz = (((unsigned)sub) << 4) + (((unsigned)(r >> 2)) << 2);
                af[sub] = *(const s16x8*)(xT + row * 68 + (((unsigned)(kk * 16 + kb8 * 4)) ^ swz));
            }
            #pragma unroll
            for (int ns = 0; ns < 4; ++ns) {
                int m = ms * 64 + ns * 16 + r;
                s16x8 bf = *(const s16x8*)(Tm + (size_t)m * LTOT + part * 1024 + t8 * 128 + kk * 32 + kb8 * 8);
                acc[0][ns] = __builtin_amdgcn_mfma_f32_16x16x32_bf16(af[0], bf, acc[0][ns], 0, 0, 0);
                acc[1][ns] = __builtin_amdgcn_mfma_f32_16x16x32_bf16(af[1], bf, acc[1][ns], 0, 0, 0);
            }
        }
        __syncthreads();
    }

    // D: row e = es*32 + sub*16 + kb8*4+g, col m = ms*64 + ns*16 + r
    float* Xb = Xp + ((size_t)part * BH + bh) * (64 * 128);
    #pragma unroll
    for (int sub = 0; sub < 2; ++sub)
        #pragma unroll
        for (int ns = 0; ns < 4; ++ns)
            #pragma unroll
            for (int g = 0; g < 4; ++g)
                Xb[(es * 32 + sub * 16 + kb8 * 4 + g) * 128 + ms * 64 + ns * 16 + r] = acc[sub][ns][g];
}

// ---------- Stage 2: mode mix (complex 64x64 per k) ----------
// grid = BH blocks (one bh), 512 threads. Re/Im planes kill the float2 4-way conflicts.
__global__ __launch_bounds__(512) void k_stage2(const float* __restrict__ Xp,
                                                const unsigned* __restrict__ wtab,
                                                const int* __restrict__ index,
                                                unsigned* __restrict__ ABo) {
    int bh = blockIdx.x;
    __shared__ float XsR[64 * 68];      // 17.4 KB Re plane [e][k]
    __shared__ float XsI[64 * 68];      // 17.4 KB Im plane [e][k]
    int t = threadIdx.x;

    #pragma unroll
    for (int i = 0; i < 4; ++i) {
        int idx = t + i * 512;          // f32x4 index over [64 e][32]
        f32x4 v = (f32x4)0.f;
        #pragma unroll
        for (int p = 0; p < 4; ++p)
            v += ((const f32x4*)(Xp + ((size_t)p * BH + bh) * 8192))[idx];
        int e = idx >> 5, k0 = (idx & 31) * 2;
        XsR[e * 68 + k0]     = v.x;
        XsI[e * 68 + k0]     = v.y;
        XsR[e * 68 + k0 + 1] = v.z;
        XsI[e * 68 + k0 + 1] = v.w;
    }
    __syncthreads();

    int k = t & 63, og = t >> 6;        // 8 groups x 8 o each
    int f = index[k];
    float cc = (f == 0 ? 1.0f : 2.0f) / (float)LTOT;
    int o0 = og * 8;
    float aR[8] = {}, aI[8] = {};
    for (int e = 0; e < 64; ++e) {
        float xr = XsR[e * 68 + k];
        float xi = XsI[e * 68 + k];
        #pragma unroll
        for (int oi = 0; oi < 8; ++oi) {
            unsigned wv = wtab[((size_t)(e * 64 + o0 + oi)) * 64 + k];
            float wr = bf2f(wv & 0xffffu);
            float wi = bf2f(wv >> 16);
            aR[oi] += xr * wr - xi * wi;
            aI[oi] += xr * wi + xi * wr;
        }
    }
    #pragma unroll
    for (int oi = 0; oi < 8; ++oi) {
        float im = (f == 0) ? 0.0f : -cc * aI[oi];
        ABo[((size_t)bh * 64 + o0 + oi) * 64 + k] = packbf(cc * aR[oi], im);
    }
}

// ---------- Stage 3: y[l][o] = sum_m AB[o][m] * Tt[l][m]  (MFMA, A=coeffs reg-cached) ----------
// grid = BH*4 (bh, quarter of L), 256 threads (4 waves), 17.4 KB LDS.
#define S3P16 136   // u16 pitch of ABl rows
__global__ __launch_bounds__(256, 4) void k_stage3(const unsigned short* __restrict__ Tt,
                                                   const unsigned* __restrict__ ABo,
                                                   float* __restrict__ y) {
    int bh = blockIdx.x >> 2, qtr = blockIdx.x & 3;
    __shared__ unsigned short ABl[64 * S3P16];   // [o=64][128 bf16 + 8 pad]
    int t = threadIdx.x;
    int lane = t & 63, wave = t >> 6;
    int r = lane & 15, kb8 = lane >> 4;

    {   // load ABo[bh] (64o x 64 u32) into LDS with padded pitch
        const unsigned* src = ABo + (size_t)bh * 4096;
        unsigned* dst = (unsigned*)ABl;
        #pragma unroll
        for (int i = 0; i < 16; ++i) {
            int idx = t + i * 256;             // over [64 o][64 u32]
            int o = idx >> 6, c = idx & 63;
            dst[o * (S3P16 / 2) + c] = src[idx];
        }
    }
    __syncthreads();

    // register-cache A-fragments: afr[es][ks], row o = es*16 + r, m-chunk ks*32 + kb8*8
    s16x8 afr[4][4];
    #pragma unroll
    for (int es = 0; es < 4; ++es)
        #pragma unroll
        for (int ks = 0; ks < 4; ++ks)
            afr[es][ks] = *(const s16x8*)(ABl + (es * 16 + r) * S3P16 + ks * 32 + kb8 * 8);

    for (int it = 0; it < 16; ++it) {
        int ltile = qtr * 1024 + it * 64 + wave * 16;
        s16x8 btf[4];
        #pragma unroll
        for (int ks = 0; ks < 4; ++ks)       // B-frag: col l = ltile + r, k = m contiguous
            btf[ks] = *(const s16x8*)(Tt + (size_t)(ltile + r) * 128 + ks * 32 + kb8 * 8);
        f32x4 acc[4];
        #pragma unroll
        for (int es = 0; es < 4; ++es) acc[es] = (f32x4)0.f;
        #pragma unroll
        for (int ks = 0; ks < 4; ++ks)
            #pragma unroll
            for (int es = 0; es < 4; ++es)
                acc[es] = __builtin_amdgcn_mfma_f32_16x16x32_bf16(afr[es][ks], btf[ks], acc[es], 0, 0, 0);
        // D: row = o = es*16 + kb8*4+g, col = l = ltile + r -> contiguous f32x4 along o
        float* yb = y + ((size_t)bh * LTOT + ltile + r) * EDIM;
        #pragma unroll
        for (int es = 0; es < 4; ++es)
            *(f32x4*)(yb + es * 16 + kb8 * 4) = acc[es];
    }
}

extern "C" void kernel_launch(void* const* d_in, const int* in_sizes, int n_in,
                              void* d_out, int out_size, void* d_ws, size_t ws_size,
                              hipStream_t stream) {
    const float* x     = (const float*)d_in[0];
    const float* wgt   = (const float*)d_in[1];
    const int*   index = (const int*)d_in[2];
    float* y  = (float*)d_out;
    float* ws = (float*)d_ws;

    // ws layout (float offsets): Tm 1MB | Tt 1MB | wt 1MB | Xp 32MB | ABo 4MB
    unsigned short* Tm = (unsigned short*)ws;
    unsigned short* Tt = (unsigned short*)(ws + 262144);
    unsigned*       wt = (unsigned*)(ws + 524288);
    float*          Xp = ws + 786432;
    unsigned*       ABo = (unsigned*)(ws + 9175040);

    hipLaunchKernelGGL(k_tables, dim3(2112),   dim3(256), 0, stream, index, wgt, Tm, Tt, wt);
    hipLaunchKernelGGL(k_stage1, dim3(BH * 4), dim3(256), 0, stream, x, Tm, Xp);
    hipLaunchKernelGGL(k_stage2, dim3(BH),     dim3(512), 0, stream, Xp, wt, index, ABo);
    hipLaunchKernelGGL(k_stage3, dim3(BH * 4), dim3(256), 0, stream, Tt, ABo, y);
}